// Round 1
// baseline (497.096 us; speedup 1.0000x reference)
//
#include <hip/hip_runtime.h>
#include <cfloat>
#include <cstdint>

#define D_FEAT 48

// Pass A: CSR row_ptr from sorted segment_ids.
// row_ptr[n] = first edge index e with seg[e] >= n; row_ptr[N] = E.
// Each node boundary is written by exactly one edge (the one that jumps past it).
__global__ void build_rowptr(const int* __restrict__ seg, int E, int N,
                             int* __restrict__ row_ptr) {
    int e = blockIdx.x * blockDim.x + threadIdx.x;
    if (e >= E) return;
    int s  = seg[e];
    int sp = (e == 0) ? -1 : seg[e - 1];
    for (int n = sp + 1; n <= s; ++n) row_ptr[n] = e;
    if (e == E - 1) {
        for (int n = s + 1; n <= N; ++n) row_ptr[n] = E;
    }
}

// Pass B: one wave (64 lanes) per node. Shuffle-reduce max and exp-sum over the
// node's contiguous edge run, then lanes 0..47 accumulate the weighted feature
// sum (lane = feature dim; per-edge 48 consecutive floats -> coalesced).
__global__ __launch_bounds__(256) void gat_reduce(
    const float* __restrict__ a, const float* __restrict__ ft,
    const int* __restrict__ row_ptr, float* __restrict__ out, int N)
{
    int lane = threadIdx.x & 63;
    int n = blockIdx.x * 4 + (threadIdx.x >> 6);
    if (n >= N) return;

    int lo  = row_ptr[n];
    int hi  = row_ptr[n + 1];
    int cnt = hi - lo;

    if (cnt <= 0) {  // empty segment: output is zero (d_out is poisoned 0xAA)
        if (lane < D_FEAT) out[(size_t)n * D_FEAT + lane] = 0.0f;
        return;
    }

    // ---- pass 1: segment max ----
    float mx = -FLT_MAX;
    for (int i = lane; i < cnt; i += 64) mx = fmaxf(mx, a[lo + i]);
    #pragma unroll
    for (int o = 32; o > 0; o >>= 1) mx = fmaxf(mx, __shfl_xor(mx, o, 64));

    // ---- pass 2: exp-sum (a is L1/L2-hot after pass 1) ----
    float s = 0.0f;
    for (int i = lane; i < cnt; i += 64) s += __expf(a[lo + i] - mx);
    #pragma unroll
    for (int o = 32; o > 0; o >>= 1) s += __shfl_xor(s, o, 64);
    float inv = 1.0f / s;

    // ---- pass 3: weighted feature accumulation ----
    float acc = 0.0f;
    const float* fp = ft + (size_t)lo * D_FEAT;
    for (int i = 0; i < cnt; ++i) {
        float w = __expf(a[lo + i] - mx) * inv;   // broadcast load + cheap exp
        if (lane < D_FEAT) acc += w * fp[(size_t)i * D_FEAT + lane];
    }
    if (lane < D_FEAT) out[(size_t)n * D_FEAT + lane] = acc;
}

extern "C" void kernel_launch(void* const* d_in, const int* in_sizes, int n_in,
                              void* d_out, int out_size, void* d_ws, size_t ws_size,
                              hipStream_t stream) {
    const float* a   = (const float*)d_in[0];
    const float* ft  = (const float*)d_in[1];
    const int*   seg = (const int*)d_in[2];
    int E = in_sizes[0];
    int N = out_size / D_FEAT;

    int* row_ptr = (int*)d_ws;  // (N+1) ints, fully overwritten every call

    build_rowptr<<<(E + 255) / 256, 256, 0, stream>>>(seg, E, N, row_ptr);
    gat_reduce<<<(N + 3) / 4, 256, 0, stream>>>(a, ft, row_ptr, (float*)d_out, N);
}

// Round 2
// 422.008 us; speedup vs baseline: 1.1779x; 1.1779x over previous
//
#include <hip/hip_runtime.h>
#include <cfloat>
#include <cstdint>

#define D_FEAT 48

// Pass A: CSR row_ptr from sorted segment_ids.
// row_ptr[n] = first edge index e with seg[e] >= n; row_ptr[N] = E.
__global__ void build_rowptr(const int* __restrict__ seg, int E, int N,
                             int* __restrict__ row_ptr) {
    int e = blockIdx.x * blockDim.x + threadIdx.x;
    if (e >= E) return;
    int s  = seg[e];
    int sp = (e == 0) ? -1 : seg[e - 1];
    for (int n = sp + 1; n <= s; ++n) row_ptr[n] = e;
    if (e == E - 1) {
        for (int n = s + 1; n <= N; ++n) row_ptr[n] = E;
    }
}

// Pass B: one wave per node. Shuffle-reduce max and exp-sum, then lanes 0..47
// accumulate the weighted feature sum with 8 independent 192-B loads in
// flight per iteration (latency-bound -> bandwidth-bound).
__global__ __launch_bounds__(256) void gat_reduce(
    const float* __restrict__ a, const float* __restrict__ ft,
    const int* __restrict__ row_ptr, float* __restrict__ out, int N)
{
    int lane = threadIdx.x & 63;
    int n = blockIdx.x * 4 + (threadIdx.x >> 6);
    if (n >= N) return;

    int lo  = row_ptr[n];
    int hi  = row_ptr[n + 1];
    int cnt = hi - lo;

    if (cnt <= 0) {  // empty segment: output zero (d_out is poisoned 0xAA)
        if (lane < D_FEAT) out[(size_t)n * D_FEAT + lane] = 0.0f;
        return;
    }

    // ---- pass 1: segment max ----
    float mx = -FLT_MAX;
    for (int i = lane; i < cnt; i += 64) mx = fmaxf(mx, a[lo + i]);
    #pragma unroll
    for (int o = 32; o > 0; o >>= 1) mx = fmaxf(mx, __shfl_xor(mx, o, 64));

    // ---- pass 2: exp-sum (a is cache-hot after pass 1) ----
    float s = 0.0f;
    for (int i = lane; i < cnt; i += 64) s += __expf(a[lo + i] - mx);
    #pragma unroll
    for (int o = 32; o > 0; o >>= 1) s += __shfl_xor(s, o, 64);
    float inv = 1.0f / s;

    // ---- pass 3: weighted feature accumulation, unroll-8 for MLP ----
    if (lane < D_FEAT) {
        float acc = 0.0f;
        const float* fp = ft + (size_t)lo * D_FEAT + lane;  // this lane's column
        const float* ap = a + lo;
        int i = 0;
        for (; i + 8 <= cnt; i += 8) {
            float f[8];
            #pragma unroll
            for (int k = 0; k < 8; ++k)          // 8 independent 192-B loads
                f[k] = fp[(size_t)(i + k) * D_FEAT];
            float w[8];
            #pragma unroll
            for (int k = 0; k < 8; ++k)          // broadcast a (L1-hot) + exp
                w[k] = __expf(ap[i + k] - mx);
            #pragma unroll
            for (int k = 0; k < 8; ++k)
                acc += w[k] * f[k];
        }
        for (; i < cnt; ++i)
            acc += __expf(ap[i] - mx) * fp[(size_t)i * D_FEAT];
        out[(size_t)n * D_FEAT + lane] = acc * inv;
    }
}

extern "C" void kernel_launch(void* const* d_in, const int* in_sizes, int n_in,
                              void* d_out, int out_size, void* d_ws, size_t ws_size,
                              hipStream_t stream) {
    const float* a   = (const float*)d_in[0];
    const float* ft  = (const float*)d_in[1];
    const int*   seg = (const int*)d_in[2];
    int E = in_sizes[0];
    int N = out_size / D_FEAT;

    int* row_ptr = (int*)d_ws;  // (N+1) ints, fully overwritten every call

    build_rowptr<<<(E + 255) / 256, 256, 0, stream>>>(seg, E, N, row_ptr);
    gat_reduce<<<(N + 3) / 4, 256, 0, stream>>>(a, ft, row_ptr, (float*)d_out, N);
}